// Round 1
// 153.714 us; speedup vs baseline: 1.0458x; 1.0458x over previous
//
#include <hip/hip_runtime.h>
#include <hip/hip_bf16.h>

typedef __attribute__((ext_vector_type(8))) short bf8v;   // 8 x bf16 (4 VGPR)
typedef __attribute__((ext_vector_type(4))) float f4v;    // 4 x f32

#define MFMA16(a,b,c) __builtin_amdgcn_mfma_f32_16x16x32_bf16((a),(b),(c),0,0,0)

#define GLD16(gp, lp) __builtin_amdgcn_global_load_lds( \
    (const __attribute__((address_space(1))) void*)(gp), \
    (__attribute__((address_space(3))) void*)(lp), 16, 0, 0)

#define DIMC   1024
#define TSEQ   2048
#define NH     16
#define NKV    4
#define HDIM   64
#define RMS_EPS 1.1920929e-07f
#define QSCALE 0.1803368801111601f   /* 0.125 * log2(e) */

__device__ __forceinline__ ushort f2bf(float f) {
  unsigned u = __builtin_bit_cast(unsigned, f);
  u = (u + 0x7FFFu + ((u >> 16) & 1u)) >> 16;
  return (ushort)u;
}
__device__ __forceinline__ float bf2f(ushort u) {
  return __builtin_bit_cast(float, (unsigned)u << 16);
}
__device__ __forceinline__ unsigned cvtpk(float lo, float hi) {
  unsigned r;
  asm("v_cvt_pk_bf16_f32 %0, %1, %2" : "=v"(r) : "v"(lo), "v"(hi));
  return r;
}

// ------- fused prep: x rmsnorm hi/lo + bf16 copy, weight hi/lo split,
//         Wv/Wp plain, rope tables. blocks 0..4095 = x, 4096.. = weights.
__global__ __launch_bounds__(256) void prep_all(
    const float* __restrict__ x,
    const float* __restrict__ Wq, const float* __restrict__ Wk,
    const float* __restrict__ Wv, const float* __restrict__ Wp,
    ushort* __restrict__ xhi, ushort* __restrict__ xlo,
    ushort* __restrict__ xb,
    ushort* __restrict__ wqkh, ushort* __restrict__ wqkl,
    ushort* __restrict__ wvb, ushort* __restrict__ wpb,
    float* __restrict__ cosT, float* __restrict__ sinT) {
  __shared__ float red[4];
  int bid = blockIdx.x, tid = threadIdx.x;
  if (bid < 4096) {                      // ---- prep_x ----
    int row = bid;
    int lane = tid & 63, w = tid >> 6;
    float4 v = ((const float4*)(x + (size_t)row * DIMC))[tid];
    float ss = v.x * v.x + v.y * v.y + v.z * v.z + v.w * v.w;
    for (int off = 32; off; off >>= 1) ss += __shfl_xor(ss, off);
    if (lane == 0) red[w] = ss;
    __syncthreads();
    float tot = red[0] + red[1] + red[2] + red[3];
    float rs = rsqrtf(tot * (1.0f / DIMC) + RMS_EPS);
    float n0 = v.x * rs, n1 = v.y * rs, n2 = v.z * rs, n3 = v.w * rs;
    ushort4 h, l, ob;
    h.x = f2bf(n0); l.x = f2bf(n0 - bf2f(h.x));
    h.y = f2bf(n1); l.y = f2bf(n1 - bf2f(h.y));
    h.z = f2bf(n2); l.z = f2bf(n2 - bf2f(h.z));
    h.w = f2bf(n3); l.w = f2bf(n3 - bf2f(h.w));
    ob.x = f2bf(v.x); ob.y = f2bf(v.y); ob.z = f2bf(v.z); ob.w = f2bf(v.w);
    ((ushort4*)(xhi + (size_t)row * DIMC))[tid] = h;
    ((ushort4*)(xlo + (size_t)row * DIMC))[tid] = l;
    ((ushort4*)(xb  + (size_t)row * DIMC))[tid] = ob;
    return;
  }
  int wb = bid - 4096;
  if (wb < 1280) {                       // hi/lo split (Wq: 1024 blk, Wk: 256)
    const float* src;
    size_t si, di;
    if (wb < 1024) { src = Wq; si = (size_t)wb * 256 + tid; di = si; }
    else { src = Wk; si = (size_t)(wb - 1024) * 256 + tid; di = 262144 + si; }
    float4 v = ((const float4*)src)[si];
    ushort4 h, l;
    h.x = f2bf(v.x); l.x = f2bf(v.x - bf2f(h.x));
    h.y = f2bf(v.y); l.y = f2bf(v.y - bf2f(h.y));
    h.z = f2bf(v.z); l.z = f2bf(v.z - bf2f(h.z));
    h.w = f2bf(v.w); l.w = f2bf(v.w - bf2f(h.w));
    ((ushort4*)wqkh)[di] = h;
    ((ushort4*)wqkl)[di] = l;
  } else if (wb < 2560) {               // plain (Wv: 256 blk, Wp: 1024)
    const float* src;
    ushort* dst;
    int i;
    if (wb < 1536) { src = Wv; dst = wvb; i = (wb - 1280) * 256 + tid; }
    else           { src = Wp; dst = wpb; i = (wb - 1536) * 256 + tid; }
    float4 v = ((const float4*)src)[i];
    ushort4 o;
    o.x = f2bf(v.x); o.y = f2bf(v.y); o.z = f2bf(v.z); o.w = f2bf(v.w);
    ((ushort4*)dst)[i] = o;
  } else {                               // rope tables (256 blk)
    int i = (wb - 2560) * 256 + tid;     // 65536 = 2048*32
    int t = i >> 5, j = i & 31;
    float inv = 1.0f / powf(10000.0f, (float)j * (1.0f / 32.0f));
    float f = (float)t * inv;
    cosT[i] = cosf(f);
    sinT[i] = sinf(f);
  }
}

// ------- merged QKV projection GEMM --------------------------------------
// grid (12, 32). N-tiles 0..9: QK (3 hi/lo segments, C=QKf N=1280);
// N-tiles 10,11: V (1 segment, C=Vf N=256). 128x128 tile, BK=64.
__global__ __launch_bounds__(256, 2)
void gemm_qkv(const ushort* __restrict__ xhi, const ushort* __restrict__ xlo,
              const ushort* __restrict__ wqkh, const ushort* __restrict__ wqkl,
              float* __restrict__ QKf, const ushort* __restrict__ xb,
              const ushort* __restrict__ wvb, float* __restrict__ Vf) {
  __shared__ __align__(16) ushort lA[128 * 64];
  __shared__ __align__(16) ushort lB[128 * 64];
  const int bx = blockIdx.x;
  const bool vpath = (bx >= 10);
  const ushort* A0 = vpath ? xb : xhi;
  const ushort* A1 = vpath ? xb : xlo;
  const ushort* B0 = vpath ? wvb : wqkh;
  const ushort* B1 = vpath ? wvb : wqkl;
  float* C = vpath ? Vf : QKf;
  const int N = vpath ? 256 : 1280;
  const int n0 = vpath ? (bx - 10) * 128 : bx * 128;
  const int nseg = vpath ? 1 : 3;

  const int t = threadIdx.x;
  const int lane = t & 63, w = t >> 6;
  const int wr = w >> 1, wc = w & 1;
  const int l15 = lane & 15, lg = lane >> 4;
  const int m0 = blockIdx.y * 128;
  const int srow = t >> 3, scp = t & 7;

  f4v acc[4][4] = {};

  for (int k0 = 0; k0 < nseg * 1024; k0 += 64) {
    const int seg = k0 >> 10, kk = k0 & 1023;
    const ushort* Ab = (seg == 1) ? A1 : A0;
    const ushort* Bb = (seg == 2) ? B1 : B0;
    for (int i = 0; i < 4; ++i) {
      int row = srow + i * 32;
      int sc = scp ^ (row & 7);
      const ushort* ga = Ab + (size_t)(m0 + row) * DIMC + kk + sc * 8;
      const ushort* gb = Bb + (size_t)(n0 + row) * DIMC + kk + sc * 8;
      GLD16(ga, &lA[w * 512 + i * 2048]);
      GLD16(gb, &lB[w * 512 + i * 2048]);
    }
    __syncthreads();
    for (int kx = 0; kx < 2; ++kx) {
      bf8v af[4], bfr[4];
      for (int m = 0; m < 4; ++m) {
        int row = wr * 64 + m * 16 + l15;
        int ch = (kx * 4 + lg) ^ (row & 7);
        af[m] = *(const bf8v*)&lA[row * 64 + ch * 8];
      }
      for (int n = 0; n < 4; ++n) {
        int row = wc * 64 + n * 16 + l15;
        int ch = (kx * 4 + lg) ^ (row & 7);
        bfr[n] = *(const bf8v*)&lB[row * 64 + ch * 8];
      }
      for (int m = 0; m < 4; ++m)
        for (int n = 0; n < 4; ++n)
          acc[m][n] = MFMA16(af[m], bfr[n], acc[m][n]);
    }
    __syncthreads();
  }

  for (int m = 0; m < 4; ++m)
    for (int n = 0; n < 4; ++n)
      for (int j = 0; j < 4; ++j) {
        int r = m0 + wr * 64 + m * 16 + lg * 4 + j;
        int c = n0 + wc * 64 + n * 16 + l15;
        C[(size_t)r * N + c] = acc[m][n][j];
      }
}

// ---------------- bf16 GEMM (final projection) ----------------
__global__ __launch_bounds__(256, 2)
void gemm_bt(const ushort* __restrict__ A0, const ushort* __restrict__ B0,
             float* __restrict__ C, int N) {
  __shared__ __align__(16) ushort lA[128 * 64];
  __shared__ __align__(16) ushort lB[128 * 64];
  const int t = threadIdx.x;
  const int lane = t & 63, w = t >> 6;
  const int wr = w >> 1, wc = w & 1;
  const int l15 = lane & 15, lg = lane >> 4;
  const int m0 = blockIdx.y * 128, n0 = blockIdx.x * 128;
  const int srow = t >> 3, scp = t & 7;

  f4v acc[4][4] = {};

  for (int k0 = 0; k0 < 1024; k0 += 64) {
    for (int i = 0; i < 4; ++i) {
      int row = srow + i * 32;
      int sc = scp ^ (row & 7);
      const ushort* ga = A0 + (size_t)(m0 + row) * DIMC + k0 + sc * 8;
      const ushort* gb = B0 + (size_t)(n0 + row) * DIMC + k0 + sc * 8;
      GLD16(ga, &lA[w * 512 + i * 2048]);
      GLD16(gb, &lB[w * 512 + i * 2048]);
    }
    __syncthreads();
    for (int kx = 0; kx < 2; ++kx) {
      bf8v af[4], bfr[4];
      for (int m = 0; m < 4; ++m) {
        int row = wr * 64 + m * 16 + l15;
        int ch = (kx * 4 + lg) ^ (row & 7);
        af[m] = *(const bf8v*)&lA[row * 64 + ch * 8];
      }
      for (int n = 0; n < 4; ++n) {
        int row = wc * 64 + n * 16 + l15;
        int ch = (kx * 4 + lg) ^ (row & 7);
        bfr[n] = *(const bf8v*)&lB[row * 64 + ch * 8];
      }
      for (int m = 0; m < 4; ++m)
        for (int n = 0; n < 4; ++n)
          acc[m][n] = MFMA16(af[m], bfr[n], acc[m][n]);
    }
    __syncthreads();
  }

  for (int m = 0; m < 4; ++m)
    for (int n = 0; n < 4; ++n)
      for (int j = 0; j < 4; ++j) {
        int r = m0 + wr * 64 + m * 16 + lg * 4 + j;
        int c = n0 + wc * 64 + n * 16 + l15;
        C[(size_t)r * N + c] = acc[m][n][j];
      }
}

// ---------------- fused post: per-head rms+rope+gain (blocks 0..4095),
//                  V transpose + normalize (blocks 4096..4351) ------------
// QKf: [m][1280]. q carries 0.125*log2e*gain (log2-domain scores).
// qhi/qlo: [b,h,t,d]; kb16: [b*4+kv][t][64] (hi only).
// vt2 [bkv][ttile][d][64], vhat_t [bkv][d][t].
__global__ __launch_bounds__(256) void post_all(
    const float* __restrict__ QKf, const float* __restrict__ cosT,
    const float* __restrict__ sinT, const float* __restrict__ qgain,
    ushort* __restrict__ qhi, ushort* __restrict__ qlo,
    ushort* __restrict__ kb16,
    const float* __restrict__ Vf, ushort* __restrict__ vt2,
    ushort* __restrict__ vhat_t) {
  __shared__ float lds[64][69];
  __shared__ float rnv[64];
  int bid = blockIdx.x;
  if (bid < 4096) {                      // ---- qkv_post ----
    int m = bid;
    int b = m >> 11, tpos = m & 2047;
    int lane = threadIdx.x & 63, w = threadIdx.x >> 6;
    int d = lane, j = d & 31;
    float sgn = (d < 32) ? 1.0f : -1.0f;
    float c = cosT[tpos * 32 + j], s = sinT[tpos * 32 + j];

    for (int i = 0; i < 4; ++i) {
      int h = w * 4 + i;
      float q = QKf[(size_t)m * 1280 + h * HDIM + d];
      float ss = q * q;
      for (int off = 32; off; off >>= 1) ss += __shfl_xor(ss, off);
      float rs = rsqrtf(ss * (1.0f / HDIM) + RMS_EPS);
      float qn = q * rs;
      float partner = __shfl_xor(qn, 32);
      float ro = (qn * c + sgn * partner * s) * (qgain[h] * QSCALE);
      ushort hi = f2bf(ro);
      ushort lo = f2bf(ro - bf2f(hi));
      size_t idx = (((size_t)b * NH + h) * TSEQ + tpos) * HDIM + d;
      qhi[idx] = hi;
      qlo[idx] = lo;
    }
    {
      int kv = w;
      float k = QKf[(size_t)m * 1280 + 1024 + kv * HDIM + d];
      float ss = k * k;
      for (int off = 32; off; off >>= 1) ss += __shfl_xor(ss, off);
      float rs = rsqrtf(ss * (1.0f / HDIM) + RMS_EPS);
      float kn = k * rs;
      float partner = __shfl_xor(kn, 32);
      float ro = kn * c + sgn * partner * s;
      kb16[((size_t)(b * NKV + kv) * TSEQ + tpos) * HDIM + d] = f2bf(ro);
    }
    return;
  }
  {                                      // ---- vtrans ----
    int vb = bid - 4096;                 // 256 = 8 bkv * 32 ttile
    int bkv = vb >> 5, tt = vb & 31;
    int b = bkv >> 2, kv = bkv & 3;
    int tid = threadIdx.x;
    for (int i = 0; i < 16; ++i) {
      int idx = i * 256 + tid;
      int tloc = idx >> 6, d = idx & 63;
      lds[d][tloc] = Vf[((size_t)(b * TSEQ + tt * 64 + tloc)) * 256 + kv * 64 + d];
    }
    __syncthreads();
    {
      int t = tid >> 2, prt = tid & 3;
      float ssum = 0.f;
      for (int dd = 0; dd < 16; ++dd) {
        float v = lds[prt * 16 + dd][t];
        ssum += v * v;
      }
      ssum += __shfl_xor(ssum, 1);
      ssum += __shfl_xor(ssum, 2);
      if (prt == 0) rnv[t] = 1.0f / fmaxf(sqrtf(ssum), 1e-12f);
    }
    __syncthreads();
    for (int i = 0; i < 16; ++i) {
      int idx = i * 256 + tid;
      int d = idx >> 6, tloc = idx & 63;
      float v = lds[d][tloc];
      vt2[(size_t)bkv * (TSEQ * 64) + tt * 4096 + d * 64 + tloc] = f2bf(v);
      vhat_t[(size_t)bkv * (TSEQ * 64) + (size_t)d * TSEQ + tt * 64 + tloc] = f2bf(v * rnv[tloc]);
    }
  }
}

// ---------------- causal GQA flash attention, LDS-staged K/V -------------
// 1024 blocks: bid = trank*32 + g*8 + xcd. All 1024 blocks are co-resident
// (4/CU at 40KB LDS); with XCD=bid%8 round-robin + sequential CU fill, CU
// group a=(cu>>2) hosts tranks {a,a+8,a+16,a+24}. Balanced bijective map:
// one tile from each quartile per CU -> constant 66 tile-iters/CU
// (was 80-4a: 35% imbalance). Big tiles still dispatched first.
// K hi-only (8KB/tile) + V^T (8KB/tile) double-buffered via global_load_lds;
// P scratch 8KB (stride 32 dw, XOR-swizzled). LDS 40KB -> 4 blocks/CU.
// QK = kh*(qh+ql) (q-lo kept, k-lo dropped: error budget has 2.5x margin).
__global__ __launch_bounds__(256, 4) void attn_kern(
    const ushort* __restrict__ qhi, const ushort* __restrict__ qlo,
    const ushort* __restrict__ kb16, const ushort* __restrict__ vt2,
    const ushort* __restrict__ vhat_t, ushort* __restrict__ ytil) {
  __shared__ __align__(16) ushort lk[2][64 * 64];    // 16 KB
  __shared__ __align__(16) ushort lv[2][64 * 64];    // 16 KB
  __shared__ __align__(16) unsigned pl[4][512];      // 8 KB
  const int t = threadIdx.x;
  const int lane = t & 63, w = t >> 6;
  const int bid = blockIdx.x;
  const int xcd = bid & 7, g = (bid >> 3) & 3, trank = bid >> 5;
  const int ta = trank & 7, tq = trank >> 3;
  const int tile = (tq == 0) ? (31 - ta)
                 : (tq == 1) ? ta
                 : (tq == 2) ? (23 - ta)
                             : (8 + ta);
  const int b = xcd >> 2, kv = xcd & 3, h = kv * 4 + g;
  const int l15 = lane & 15, lg = lane >> 4;
  const int q0 = tile * 64 + w * 16;
  const int ntile = tile + 1;
  const int t3 = t >> 3, tc8 = t & 7;
  const int rx = l15 & 7;
  const int pswz = rx << 2;

  const size_t qoff = (((size_t)(b * NH + h)) * TSEQ + q0 + l15) * HDIM;
  bf8v bq0h = *(const bf8v*)(qhi + qoff + lg * 8);
  bf8v bq1h = *(const bf8v*)(qhi + qoff + 32 + lg * 8);
  bf8v bq0l = *(const bf8v*)(qlo + qoff + lg * 8);
  bf8v bq1l = *(const bf8v*)(qlo + qoff + 32 + lg * 8);

  const ushort* kb = kb16 + (size_t)(b * NKV + kv) * TSEQ * 64;
  const ushort* vb = vt2 + (size_t)(b * NKV + kv) * TSEQ * 64;
  unsigned* pw = &pl[w][0];

#define STAGE(BUF, IT) do { \
    _Pragma("unroll") \
    for (int i = 0; i < 2; ++i) { \
      int row = i * 32 + t3; \
      int sc = tc8 ^ (row & 7); \
      GLD16(kb + (size_t)((IT) * 64 + row) * 64 + sc * 8, \
            &lk[BUF][(i * 32 + (w << 3)) * 64]); \
      GLD16(vb + (size_t)(IT) * 4096 + row * 64 + sc * 8, \
            &lv[BUF][(i * 32 + (w << 3)) * 64]); \
    } } while (0)

  STAGE(0, 0);

  f4v y[4] = {};
  float mrow = -1e30f, lrow = 0.f;

#pragma unroll 1
  for (int it = 0; it < ntile; ++it) {
    const int cur = it & 1;
    __syncthreads();                       // drains prefetch of buf[cur]
    if (it + 1 < ntile) STAGE(cur ^ 1, it + 1);  // flies under this compute

    const ushort* lkc = &lk[cur][0];
    const ushort* lvc = &lv[cur][0];
    const int kv0 = it * 64;

    // QK: kh*(qh+ql), one accumulator per key-group (log2-domain scores)
    f4v s[4];
    __builtin_amdgcn_s_setprio(1);
#pragma unroll
    for (int n = 0; n < 4; ++n) {
      const ushort* krow = lkc + (n * 16 + l15) * 64;
      bf8v kh0 = *(const bf8v*)&krow[((0 + lg) ^ rx) * 8];
      bf8v kh1 = *(const bf8v*)&krow[((4 + lg) ^ rx) * 8];
      f4v z = {};
      f4v acc = MFMA16(kh0, bq0h, z);
      acc = MFMA16(kh1, bq1h, acc);
      acc = MFMA16(kh0, bq0l, acc);
      acc = MFMA16(kh1, bq1l, acc);
      s[n] = acc;
    }
    __builtin_amdgcn_s_setprio(0);

    // mask + max; lane holds S^T[key=kv0+16n+4lg+j][q=q0+l15], log2 units
    const bool need_mask = (it == ntile - 1);
    float mloc = -1e30f;
#pragma unroll
    for (int n = 0; n < 4; ++n)
#pragma unroll
      for (int j = 0; j < 4; ++j) {
        float v = s[n][j];
        if (need_mask && (kv0 + n * 16 + lg * 4 + j > q0 + l15)) v = -1e30f;
        s[n][j] = v;
        mloc = fmaxf(mloc, v);
      }
    mloc = fmaxf(mloc, __shfl_xor(mloc, 16));
    mloc = fmaxf(mloc, __shfl_xor(mloc, 32));
    if (__any(mloc > mrow + 11.5f)) {      // defer-max (log2 units)
      float mnew = fmaxf(mrow, mloc);
      float scf = exp2f(mrow - mnew);
      lrow *= scf;
#pragma unroll
      for (int n = 0; n < 4; ++n) y[n] *= scf;
      mrow = mnew;
    }
    float rs = 0.f;
#pragma unroll
    for (int n = 0; n < 4; ++n)
#pragma unroll
      for (int j = 0; j < 4; ++j) {
        float e = exp2f(s[n][j] - mrow);
        s[n][j] = e;
        rs += e;
      }
    rs += __shfl_xor(rs, 16);
    rs += __shfl_xor(rs, 32);
    lrow += rs;

    // P^T -> LDS (per-wave, stride 32 dw, XOR-swizzled) via cvt_pk
#pragma unroll
    for (int n = 0; n < 4; ++n) {
      uint2 pk;
      pk.x = cvtpk(s[n][0], s[n][1]);
      pk.y = cvtpk(s[n][2], s[n][3]);
      *(uint2*)&pw[l15 * 32 + ((8 * n + 2 * lg) ^ pswz)] = pk;
    }
    asm volatile("s_waitcnt lgkmcnt(0)" ::: "memory");
    bf8v pb0 = *(const bf8v*)&pw[l15 * 32 + ((lg * 4) ^ pswz)];
    bf8v pb1 = *(const bf8v*)&pw[l15 * 32 + ((16 + lg * 4) ^ pswz)];
    __builtin_amdgcn_s_setprio(1);
#pragma unroll
    for (int n = 0; n < 4; ++n) {
      const ushort* vrow = lvc + (n * 16 + l15) * 64;
      bf8v va0 = *(const bf8v*)&vrow[((0 + lg) ^ rx) * 8];
      bf8v va1 = *(const bf8v*)&vrow[((4 + lg) ^ rx) * 8];
      y[n] = MFMA16(va0, pb0, y[n]);
      y[n] = MFMA16(va1, pb1, y[n]);
    }
    __builtin_amdgcn_s_setprio(0);
  }
#undef STAGE

  // epilogue: y^T[d][q]/l, v-hat removal, transpose via swizzled LDS, store
  {
    float inv = 1.0f / lrow;
    const ushort* vh = vhat_t + (size_t)(b * NKV + kv) * TSEQ * 64;
    ushort* yw = (ushort*)pw;
    float vv[4][4];
    float dp = 0.f;
#pragma unroll
    for (int n = 0; n < 4; ++n)
#pragma unroll
      for (int j = 0; j < 4; ++j) {
        int d = n * 16 + lg * 4 + j;
        float yv = y[n][j] * inv;
        y[n][j] = yv;
        vv[n][j] = bf2f(vh[(size_t)d * TSEQ + q0 + l15]);
        dp += yv * vv[n][j];
      }
    dp += __shfl_xor(dp, 16);
    dp += __shfl_xor(dp, 32);
#pragma unroll
    for (int n = 0; n < 4; ++n)
#pragma unroll
      for (int j = 0; j < 4; ++j) {
        int d = n * 16 + lg * 4 + j;
        yw[l15 * 64 + (((d >> 3) ^ rx) << 3) + (d & 7)] = f2bf(y[n][j] - dp * vv[n][j]);
      }
    asm volatile("s_waitcnt lgkmcnt(0)" ::: "memory");
    int row = lane >> 2, quad = lane & 3;
    bf8v y0 = *(const bf8v*)(yw + row * 64 + ((quad ^ (row & 7)) << 3));
    bf8v y1 = *(const bf8v*)(yw + row * 64 + (((quad + 4) ^ (row & 7)) << 3));
    size_t gbase = ((size_t)(b * TSEQ + q0 + row)) * DIMC + h * HDIM + quad * 8;
    *(bf8v*)(ytil + gbase) = y0;
    *(bf8v*)(ytil + gbase + 32) = y1;
  }
}

extern "C" void kernel_launch(void* const* d_in, const int* in_sizes, int n_in,
                              void* d_out, int out_size, void* d_ws, size_t ws_size,
                              hipStream_t stream) {
  (void)in_sizes; (void)n_in; (void)out_size; (void)ws_size;
  const float* x  = (const float*)d_in[0];
  const float* Wq = (const float*)d_in[1];
  const float* Wk = (const float*)d_in[2];
  const float* Wv = (const float*)d_in[3];
  const float* Wp = (const float*)d_in[4];
  const float* qg = (const float*)d_in[5];
  float* out = (float*)d_out;
  char* ws = (char*)d_ws;
  const size_t KB = 1024, MB = 1ull << 20;

  ushort* xhi = (ushort*)(ws);                         // 8 MiB -> qhi
  ushort* xlo = (ushort*)(ws + 8 * MB);                // 8 MiB -> qlo
  ushort* xb  = (ushort*)(ws + 16 * MB);               // 8 MiB -> ytil
  ushort* wqkh = (ushort*)(ws + 24 * MB);              // 2.5 MiB (Wq|Wk hi)
  ushort* wqkl = (ushort*)(ws + 26 * MB + 512 * KB);   // 2.5 MiB (Wq|Wk lo)
  ushort* wvb = (ushort*)(ws + 29 * MB);               // 0.5 MiB
  ushort* wpb = (ushort*)(ws + 29 * MB + 512 * KB);    // 2 MiB
  float*  cosT = (float*)(ws + 31 * MB + 512 * KB);    // 0.25 MiB
  float*  sinT = (float*)(ws + 31 * MB + 768 * KB);    // 0.25 MiB
  float*  QKf  = (float*)(ws + 32 * MB);               // 20 MiB [4096][1280]
  ushort* kb16 = (ushort*)(ws + 52 * MB);              // 2 MiB
  ushort* vt2  = (ushort*)(ws + 54 * MB);              // 2 MiB
  ushort* vhat = (ushort*)(ws + 56 * MB);              // 2 MiB (total 58)

  float*  Vf   = out;    // d_out as f32 scratch for V projection (4 MiB)
  ushort* qhb  = xhi;    // reuse after projections
  ushort* qlb  = xlo;
  ushort* ytil = xb;

  prep_all<<<6912, 256, 0, stream>>>(x, Wq, Wk, Wv, Wp, xhi, xlo, xb,
                                     wqkh, wqkl, wvb, wpb, cosT, sinT);

  gemm_qkv<<<dim3(12, 32), 256, 0, stream>>>(xhi, xlo, wqkh, wqkl, QKf,
                                             xb, wvb, Vf);

  post_all<<<4352, 256, 0, stream>>>(QKf, cosT, sinT, qg, qhb, qlb, kb16,
                                     Vf, vt2, vhat);
  attn_kern<<<1024, 256, 0, stream>>>(qhb, qlb, kb16, vt2, vhat, ytil);
  gemm_bt<<<dim3(8, 32), 256, 0, stream>>>(ytil, wpb, out, 1024);
}

// Round 2
// 143.615 us; speedup vs baseline: 1.1194x; 1.0703x over previous
//
#include <hip/hip_runtime.h>
#include <hip/hip_bf16.h>

typedef __attribute__((ext_vector_type(8))) short bf8v;   // 8 x bf16 (4 VGPR)
typedef __attribute__((ext_vector_type(4))) float f4v;    // 4 x f32

#define MFMA16(a,b,c) __builtin_amdgcn_mfma_f32_16x16x32_bf16((a),(b),(c),0,0,0)

#define GLD16(gp, lp) __builtin_amdgcn_global_load_lds( \
    (const __attribute__((address_space(1))) void*)(gp), \
    (__attribute__((address_space(3))) void*)(lp), 16, 0, 0)

#define DIMC   1024
#define TSEQ   2048
#define NH     16
#define NKV    4
#define HDIM   64
#define RMS_EPS 1.1920929e-07f
#define QSCALE 0.1803368801111601f   /* 0.125 * log2(e) */

__device__ __forceinline__ ushort f2bf(float f) {
  unsigned u = __builtin_bit_cast(unsigned, f);
  u = (u + 0x7FFFu + ((u >> 16) & 1u)) >> 16;
  return (ushort)u;
}
__device__ __forceinline__ float bf2f(ushort u) {
  return __builtin_bit_cast(float, (unsigned)u << 16);
}
__device__ __forceinline__ unsigned cvtpk(float lo, float hi) {
  unsigned r;
  asm("v_cvt_pk_bf16_f32 %0, %1, %2" : "=v"(r) : "v"(lo), "v"(hi));
  return r;
}

// ------- fused prep: x rmsnorm hi/lo + bf16 copy, weight hi/lo split,
//         Wv/Wp plain, rope tables. blocks 0..4095 = x, 4096.. = weights.
__global__ __launch_bounds__(256) void prep_all(
    const float* __restrict__ x,
    const float* __restrict__ Wq, const float* __restrict__ Wk,
    const float* __restrict__ Wv, const float* __restrict__ Wp,
    ushort* __restrict__ xhi, ushort* __restrict__ xlo,
    ushort* __restrict__ xb,
    ushort* __restrict__ wqkh, ushort* __restrict__ wqkl,
    ushort* __restrict__ wvb, ushort* __restrict__ wpb,
    float* __restrict__ cosT, float* __restrict__ sinT) {
  __shared__ float red[4];
  int bid = blockIdx.x, tid = threadIdx.x;
  if (bid < 4096) {                      // ---- prep_x ----
    int row = bid;
    int lane = tid & 63, w = tid >> 6;
    float4 v = ((const float4*)(x + (size_t)row * DIMC))[tid];
    float ss = v.x * v.x + v.y * v.y + v.z * v.z + v.w * v.w;
    for (int off = 32; off; off >>= 1) ss += __shfl_xor(ss, off);
    if (lane == 0) red[w] = ss;
    __syncthreads();
    float tot = red[0] + red[1] + red[2] + red[3];
    float rs = rsqrtf(tot * (1.0f / DIMC) + RMS_EPS);
    float n0 = v.x * rs, n1 = v.y * rs, n2 = v.z * rs, n3 = v.w * rs;
    ushort4 h, l, ob;
    h.x = f2bf(n0); l.x = f2bf(n0 - bf2f(h.x));
    h.y = f2bf(n1); l.y = f2bf(n1 - bf2f(h.y));
    h.z = f2bf(n2); l.z = f2bf(n2 - bf2f(h.z));
    h.w = f2bf(n3); l.w = f2bf(n3 - bf2f(h.w));
    ob.x = f2bf(v.x); ob.y = f2bf(v.y); ob.z = f2bf(v.z); ob.w = f2bf(v.w);
    ((ushort4*)(xhi + (size_t)row * DIMC))[tid] = h;
    ((ushort4*)(xlo + (size_t)row * DIMC))[tid] = l;
    ((ushort4*)(xb  + (size_t)row * DIMC))[tid] = ob;
    return;
  }
  int wb = bid - 4096;
  if (wb < 1280) {                       // hi/lo split (Wq: 1024 blk, Wk: 256)
    const float* src;
    size_t si, di;
    if (wb < 1024) { src = Wq; si = (size_t)wb * 256 + tid; di = si; }
    else { src = Wk; si = (size_t)(wb - 1024) * 256 + tid; di = 262144 + si; }
    float4 v = ((const float4*)src)[si];
    ushort4 h, l;
    h.x = f2bf(v.x); l.x = f2bf(v.x - bf2f(h.x));
    h.y = f2bf(v.y); l.y = f2bf(v.y - bf2f(h.y));
    h.z = f2bf(v.z); l.z = f2bf(v.z - bf2f(h.z));
    h.w = f2bf(v.w); l.w = f2bf(v.w - bf2f(h.w));
    ((ushort4*)wqkh)[di] = h;
    ((ushort4*)wqkl)[di] = l;
  } else if (wb < 2560) {               // plain (Wv: 256 blk, Wp: 1024)
    const float* src;
    ushort* dst;
    int i;
    if (wb < 1536) { src = Wv; dst = wvb; i = (wb - 1280) * 256 + tid; }
    else           { src = Wp; dst = wpb; i = (wb - 1536) * 256 + tid; }
    float4 v = ((const float4*)src)[i];
    ushort4 o;
    o.x = f2bf(v.x); o.y = f2bf(v.y); o.z = f2bf(v.z); o.w = f2bf(v.w);
    ((ushort4*)dst)[i] = o;
  } else {                               // rope tables (256 blk)
    int i = (wb - 2560) * 256 + tid;     // 65536 = 2048*32
    int t = i >> 5, j = i & 31;
    float inv = 1.0f / powf(10000.0f, (float)j * (1.0f / 32.0f));
    float f = (float)t * inv;
    cosT[i] = cosf(f);
    sinT[i] = sinf(f);
  }
}

// ------- merged QKV projection GEMM, uniform-work seg-split --------------
// 704 blocks of 128x128 tiles, BK=64. Three unit kinds:
//   seg0  (16 steps): xhi*Wh           -> QKf (fp32, N=1280)   [320 units]
//   seg12 (32 steps): xlo*Wh + xhi*Wl  -> QKc (bf16 partial)   [320 units]
//   V     (16 steps): xb*Wv            -> Vf  (fp32, N=256)    [ 64 units]
// Dispatch order vs mod-256 CU round-robin gives every CU exactly 64 steps:
//   bids   0..255: seg12   (CU c<192 gets {32,16,16}; c>=192 first 32)
//   bids 256..447: 16-step
//   bids 448..511: seg12   (CU 192..255 second 32 -> {32,32})
//   bids 512..703: 16-step
// 3 blocks/CU resident (96KB LDS) -> latency shared 3-4x vs old 1.5x.
// QKc is the hi/lo correction (~2^-9 relative), bf16 storage is lossless
// at the error budget.
__global__ __launch_bounds__(256, 3)
void gemm_qkv(const ushort* __restrict__ xhi, const ushort* __restrict__ xlo,
              const ushort* __restrict__ wqkh, const ushort* __restrict__ wqkl,
              float* __restrict__ QKf, ushort* __restrict__ QKc,
              const ushort* __restrict__ xb, const ushort* __restrict__ wvb,
              float* __restrict__ Vf) {
  __shared__ __align__(16) ushort lA[128 * 64];
  __shared__ __align__(16) ushort lB[128 * 64];
  const int bid = blockIdx.x;
  int u;
  bool big;
  if (bid < 256)      { big = true;  u = bid; }
  else if (bid < 448) { big = false; u = bid - 256; }
  else if (bid < 512) { big = true;  u = 256 + (bid - 448); }
  else                { big = false; u = 192 + (bid - 512); }

  const ushort *Ap0, *Bp0, *Ap1, *Bp1;
  float* Cf = QKf;
  int N = 1280, nsteps, mt, n0;
  if (big) {                 // seg1+seg2 partial -> QKc
    mt = u / 10; n0 = (u % 10) * 128;
    Ap0 = xlo; Bp0 = wqkh; Ap1 = xhi; Bp1 = wqkl; nsteps = 32;
  } else if (u < 320) {      // seg0 -> QKf
    mt = u / 10; n0 = (u % 10) * 128;
    Ap0 = xhi; Bp0 = wqkh; Ap1 = Ap0; Bp1 = Bp0; nsteps = 16;
  } else {                   // V -> Vf
    int v = u - 320; mt = v >> 1; n0 = (v & 1) * 128;
    Ap0 = xb; Bp0 = wvb; Ap1 = Ap0; Bp1 = Bp0; nsteps = 16;
    Cf = Vf; N = 256;
  }
  const int m0 = mt * 128;

  const int t = threadIdx.x;
  const int lane = t & 63, w = t >> 6;
  const int wr = w >> 1, wc = w & 1;
  const int l15 = lane & 15, lg = lane >> 4;
  const int srow = t >> 3, scp = t & 7;

  f4v acc[4][4] = {};

  for (int s = 0; s < nsteps; ++s) {
    const ushort* Ab = (s < 16) ? Ap0 : Ap1;
    const ushort* Bb = (s < 16) ? Bp0 : Bp1;
    const int kk = (s & 15) * 64;
    for (int i = 0; i < 4; ++i) {
      int row = srow + i * 32;
      int sc = scp ^ (row & 7);
      const ushort* ga = Ab + (size_t)(m0 + row) * DIMC + kk + sc * 8;
      const ushort* gb = Bb + (size_t)(n0 + row) * DIMC + kk + sc * 8;
      GLD16(ga, &lA[w * 512 + i * 2048]);
      GLD16(gb, &lB[w * 512 + i * 2048]);
    }
    __syncthreads();
    for (int kx = 0; kx < 2; ++kx) {
      bf8v af[4], bfr[4];
      for (int m = 0; m < 4; ++m) {
        int row = wr * 64 + m * 16 + l15;
        int ch = (kx * 4 + lg) ^ (row & 7);
        af[m] = *(const bf8v*)&lA[row * 64 + ch * 8];
      }
      for (int n = 0; n < 4; ++n) {
        int row = wc * 64 + n * 16 + l15;
        int ch = (kx * 4 + lg) ^ (row & 7);
        bfr[n] = *(const bf8v*)&lB[row * 64 + ch * 8];
      }
      for (int m = 0; m < 4; ++m)
        for (int n = 0; n < 4; ++n)
          acc[m][n] = MFMA16(af[m], bfr[n], acc[m][n]);
    }
    __syncthreads();
  }

  if (big) {
    for (int m = 0; m < 4; ++m)
      for (int n = 0; n < 4; ++n)
        for (int j = 0; j < 4; ++j) {
          int r = m0 + wr * 64 + m * 16 + lg * 4 + j;
          int c = n0 + wc * 64 + n * 16 + l15;
          QKc[(size_t)r * 1280 + c] = f2bf(acc[m][n][j]);
        }
  } else {
    for (int m = 0; m < 4; ++m)
      for (int n = 0; n < 4; ++n)
        for (int j = 0; j < 4; ++j) {
          int r = m0 + wr * 64 + m * 16 + lg * 4 + j;
          int c = n0 + wc * 64 + n * 16 + l15;
          Cf[(size_t)r * N + c] = acc[m][n][j];
        }
  }
}

// ---------------- bf16 GEMM (final projection) ----------------
__global__ __launch_bounds__(256, 2)
void gemm_bt(const ushort* __restrict__ A0, const ushort* __restrict__ B0,
             float* __restrict__ C, int N) {
  __shared__ __align__(16) ushort lA[128 * 64];
  __shared__ __align__(16) ushort lB[128 * 64];
  const int t = threadIdx.x;
  const int lane = t & 63, w = t >> 6;
  const int wr = w >> 1, wc = w & 1;
  const int l15 = lane & 15, lg = lane >> 4;
  const int m0 = blockIdx.y * 128, n0 = blockIdx.x * 128;
  const int srow = t >> 3, scp = t & 7;

  f4v acc[4][4] = {};

  for (int k0 = 0; k0 < 1024; k0 += 64) {
    for (int i = 0; i < 4; ++i) {
      int row = srow + i * 32;
      int sc = scp ^ (row & 7);
      const ushort* ga = A0 + (size_t)(m0 + row) * DIMC + k0 + sc * 8;
      const ushort* gb = B0 + (size_t)(n0 + row) * DIMC + k0 + sc * 8;
      GLD16(ga, &lA[w * 512 + i * 2048]);
      GLD16(gb, &lB[w * 512 + i * 2048]);
    }
    __syncthreads();
    for (int kx = 0; kx < 2; ++kx) {
      bf8v af[4], bfr[4];
      for (int m = 0; m < 4; ++m) {
        int row = wr * 64 + m * 16 + l15;
        int ch = (kx * 4 + lg) ^ (row & 7);
        af[m] = *(const bf8v*)&lA[row * 64 + ch * 8];
      }
      for (int n = 0; n < 4; ++n) {
        int row = wc * 64 + n * 16 + l15;
        int ch = (kx * 4 + lg) ^ (row & 7);
        bfr[n] = *(const bf8v*)&lB[row * 64 + ch * 8];
      }
      for (int m = 0; m < 4; ++m)
        for (int n = 0; n < 4; ++n)
          acc[m][n] = MFMA16(af[m], bfr[n], acc[m][n]);
    }
    __syncthreads();
  }

  for (int m = 0; m < 4; ++m)
    for (int n = 0; n < 4; ++n)
      for (int j = 0; j < 4; ++j) {
        int r = m0 + wr * 64 + m * 16 + lg * 4 + j;
        int c = n0 + wc * 64 + n * 16 + l15;
        C[(size_t)r * N + c] = acc[m][n][j];
      }
}

// ---------------- fused post: per-head rms+rope+gain (blocks 0..4095),
//                  V transpose + normalize (blocks 4096..4351) ------------
// q/k = QKf (seg0) + bf2f(QKc) (seg1+seg2 correction).
__global__ __launch_bounds__(256) void post_all(
    const float* __restrict__ QKf, const ushort* __restrict__ QKc,
    const float* __restrict__ cosT,
    const float* __restrict__ sinT, const float* __restrict__ qgain,
    ushort* __restrict__ qhi, ushort* __restrict__ qlo,
    ushort* __restrict__ kb16,
    const float* __restrict__ Vf, ushort* __restrict__ vt2,
    ushort* __restrict__ vhat_t) {
  __shared__ float lds[64][69];
  __shared__ float rnv[64];
  int bid = blockIdx.x;
  if (bid < 4096) {                      // ---- qkv_post ----
    int m = bid;
    int b = m >> 11, tpos = m & 2047;
    int lane = threadIdx.x & 63, w = threadIdx.x >> 6;
    int d = lane, j = d & 31;
    float sgn = (d < 32) ? 1.0f : -1.0f;
    float c = cosT[tpos * 32 + j], s = sinT[tpos * 32 + j];

    for (int i = 0; i < 4; ++i) {
      int h = w * 4 + i;
      size_t base = (size_t)m * 1280 + h * HDIM + d;
      float q = QKf[base] + bf2f(QKc[base]);
      float ss = q * q;
      for (int off = 32; off; off >>= 1) ss += __shfl_xor(ss, off);
      float rs = rsqrtf(ss * (1.0f / HDIM) + RMS_EPS);
      float qn = q * rs;
      float partner = __shfl_xor(qn, 32);
      float ro = (qn * c + sgn * partner * s) * (qgain[h] * QSCALE);
      ushort hi = f2bf(ro);
      ushort lo = f2bf(ro - bf2f(hi));
      size_t idx = (((size_t)b * NH + h) * TSEQ + tpos) * HDIM + d;
      qhi[idx] = hi;
      qlo[idx] = lo;
    }
    {
      int kv = w;
      size_t base = (size_t)m * 1280 + 1024 + kv * HDIM + d;
      float k = QKf[base] + bf2f(QKc[base]);
      float ss = k * k;
      for (int off = 32; off; off >>= 1) ss += __shfl_xor(ss, off);
      float rs = rsqrtf(ss * (1.0f / HDIM) + RMS_EPS);
      float kn = k * rs;
      float partner = __shfl_xor(kn, 32);
      float ro = kn * c + sgn * partner * s;
      kb16[((size_t)(b * NKV + kv) * TSEQ + tpos) * HDIM + d] = f2bf(ro);
    }
    return;
  }
  {                                      // ---- vtrans ----
    int vb = bid - 4096;                 // 256 = 8 bkv * 32 ttile
    int bkv = vb >> 5, tt = vb & 31;
    int b = bkv >> 2, kv = bkv & 3;
    int tid = threadIdx.x;
    for (int i = 0; i < 16; ++i) {
      int idx = i * 256 + tid;
      int tloc = idx >> 6, d = idx & 63;
      lds[d][tloc] = Vf[((size_t)(b * TSEQ + tt * 64 + tloc)) * 256 + kv * 64 + d];
    }
    __syncthreads();
    {
      int t = tid >> 2, prt = tid & 3;
      float ssum = 0.f;
      for (int dd = 0; dd < 16; ++dd) {
        float v = lds[prt * 16 + dd][t];
        ssum += v * v;
      }
      ssum += __shfl_xor(ssum, 1);
      ssum += __shfl_xor(ssum, 2);
      if (prt == 0) rnv[t] = 1.0f / fmaxf(sqrtf(ssum), 1e-12f);
    }
    __syncthreads();
    for (int i = 0; i < 16; ++i) {
      int idx = i * 256 + tid;
      int d = idx >> 6, tloc = idx & 63;
      float v = lds[d][tloc];
      vt2[(size_t)bkv * (TSEQ * 64) + tt * 4096 + d * 64 + tloc] = f2bf(v);
      vhat_t[(size_t)bkv * (TSEQ * 64) + (size_t)d * TSEQ + tt * 64 + tloc] = f2bf(v * rnv[tloc]);
    }
  }
}

// ---------------- causal GQA flash attention, LDS-staged K/V -------------
// 1024 blocks: bid = trank*32 + g*8 + xcd; balanced bijective trank->tile.
// K hi-only (8KB/tile) + V^T (8KB/tile) double-buffered via global_load_lds;
// P scratch 8KB (stride 32 dw, XOR-swizzled). LDS 40KB -> 4 blocks/CU.
// QK = kh*(qh+ql) (q-lo kept, k-lo dropped: error budget has 2.5x margin).
__global__ __launch_bounds__(256, 4) void attn_kern(
    const ushort* __restrict__ qhi, const ushort* __restrict__ qlo,
    const ushort* __restrict__ kb16, const ushort* __restrict__ vt2,
    const ushort* __restrict__ vhat_t, ushort* __restrict__ ytil) {
  __shared__ __align__(16) ushort lk[2][64 * 64];    // 16 KB
  __shared__ __align__(16) ushort lv[2][64 * 64];    // 16 KB
  __shared__ __align__(16) unsigned pl[4][512];      // 8 KB
  const int t = threadIdx.x;
  const int lane = t & 63, w = t >> 6;
  const int bid = blockIdx.x;
  const int xcd = bid & 7, g = (bid >> 3) & 3, trank = bid >> 5;
  const int ta = trank & 7, tq = trank >> 3;
  const int tile = (tq == 0) ? (31 - ta)
                 : (tq == 1) ? ta
                 : (tq == 2) ? (23 - ta)
                             : (8 + ta);
  const int b = xcd >> 2, kv = xcd & 3, h = kv * 4 + g;
  const int l15 = lane & 15, lg = lane >> 4;
  const int q0 = tile * 64 + w * 16;
  const int ntile = tile + 1;
  const int t3 = t >> 3, tc8 = t & 7;
  const int rx = l15 & 7;
  const int pswz = rx << 2;

  const size_t qoff = (((size_t)(b * NH + h)) * TSEQ + q0 + l15) * HDIM;
  bf8v bq0h = *(const bf8v*)(qhi + qoff + lg * 8);
  bf8v bq1h = *(const bf8v*)(qhi + qoff + 32 + lg * 8);
  bf8v bq0l = *(const bf8v*)(qlo + qoff + lg * 8);
  bf8v bq1l = *(const bf8v*)(qlo + qoff + 32 + lg * 8);

  const ushort* kb = kb16 + (size_t)(b * NKV + kv) * TSEQ * 64;
  const ushort* vb = vt2 + (size_t)(b * NKV + kv) * TSEQ * 64;
  unsigned* pw = &pl[w][0];

#define STAGE(BUF, IT) do { \
    _Pragma("unroll") \
    for (int i = 0; i < 2; ++i) { \
      int row = i * 32 + t3; \
      int sc = tc8 ^ (row & 7); \
      GLD16(kb + (size_t)((IT) * 64 + row) * 64 + sc * 8, \
            &lk[BUF][(i * 32 + (w << 3)) * 64]); \
      GLD16(vb + (size_t)(IT) * 4096 + row * 64 + sc * 8, \
            &lv[BUF][(i * 32 + (w << 3)) * 64]); \
    } } while (0)

  STAGE(0, 0);

  f4v y[4] = {};
  float mrow = -1e30f, lrow = 0.f;

#pragma unroll 1
  for (int it = 0; it < ntile; ++it) {
    const int cur = it & 1;
    __syncthreads();                       // drains prefetch of buf[cur]
    if (it + 1 < ntile) STAGE(cur ^ 1, it + 1);  // flies under this compute

    const ushort* lkc = &lk[cur][0];
    const ushort* lvc = &lv[cur][0];
    const int kv0 = it * 64;

    // QK: kh*(qh+ql), one accumulator per key-group (log2-domain scores)
    f4v s[4];
    __builtin_amdgcn_s_setprio(1);
#pragma unroll
    for (int n = 0; n < 4; ++n) {
      const ushort* krow = lkc + (n * 16 + l15) * 64;
      bf8v kh0 = *(const bf8v*)&krow[((0 + lg) ^ rx) * 8];
      bf8v kh1 = *(const bf8v*)&krow[((4 + lg) ^ rx) * 8];
      f4v z = {};
      f4v acc = MFMA16(kh0, bq0h, z);
      acc = MFMA16(kh1, bq1h, acc);
      acc = MFMA16(kh0, bq0l, acc);
      acc = MFMA16(kh1, bq1l, acc);
      s[n] = acc;
    }
    __builtin_amdgcn_s_setprio(0);

    // mask + max; lane holds S^T[key=kv0+16n+4lg+j][q=q0+l15], log2 units
    const bool need_mask = (it == ntile - 1);
    float mloc = -1e30f;
#pragma unroll
    for (int n = 0; n < 4; ++n)
#pragma unroll
      for (int j = 0; j < 4; ++j) {
        float v = s[n][j];
        if (need_mask && (kv0 + n * 16 + lg * 4 + j > q0 + l15)) v = -1e30f;
        s[n][j] = v;
        mloc = fmaxf(mloc, v);
      }
    mloc = fmaxf(mloc, __shfl_xor(mloc, 16));
    mloc = fmaxf(mloc, __shfl_xor(mloc, 32));
    if (__any(mloc > mrow + 11.5f)) {      // defer-max (log2 units)
      float mnew = fmaxf(mrow, mloc);
      float scf = exp2f(mrow - mnew);
      lrow *= scf;
#pragma unroll
      for (int n = 0; n < 4; ++n) y[n] *= scf;
      mrow = mnew;
    }
    float rs = 0.f;
#pragma unroll
    for (int n = 0; n < 4; ++n)
#pragma unroll
      for (int j = 0; j < 4; ++j) {
        float e = exp2f(s[n][j] - mrow);
        s[n][j] = e;
        rs += e;
      }
    rs += __shfl_xor(rs, 16);
    rs += __shfl_xor(rs, 32);
    lrow += rs;

    // P^T -> LDS (per-wave, stride 32 dw, XOR-swizzled) via cvt_pk
#pragma unroll
    for (int n = 0; n < 4; ++n) {
      uint2 pk;
      pk.x = cvtpk(s[n][0], s[n][1]);
      pk.y = cvtpk(s[n][2], s[n][3]);
      *(uint2*)&pw[l15 * 32 + ((8 * n + 2 * lg) ^ pswz)] = pk;
    }
    asm volatile("s_waitcnt lgkmcnt(0)" ::: "memory");
    bf8v pb0 = *(const bf8v*)&pw[l15 * 32 + ((lg * 4) ^ pswz)];
    bf8v pb1 = *(const bf8v*)&pw[l15 * 32 + ((16 + lg * 4) ^ pswz)];
    __builtin_amdgcn_s_setprio(1);
#pragma unroll
    for (int n = 0; n < 4; ++n) {
      const ushort* vrow = lvc + (n * 16 + l15) * 64;
      bf8v va0 = *(const bf8v*)&vrow[((0 + lg) ^ rx) * 8];
      bf8v va1 = *(const bf8v*)&vrow[((4 + lg) ^ rx) * 8];
      y[n] = MFMA16(va0, pb0, y[n]);
      y[n] = MFMA16(va1, pb1, y[n]);
    }
    __builtin_amdgcn_s_setprio(0);
  }
#undef STAGE

  // epilogue: y^T[d][q]/l, v-hat removal, transpose via swizzled LDS, store
  {
    float inv = 1.0f / lrow;
    const ushort* vh = vhat_t + (size_t)(b * NKV + kv) * TSEQ * 64;
    ushort* yw = (ushort*)pw;
    float vv[4][4];
    float dp = 0.f;
#pragma unroll
    for (int n = 0; n < 4; ++n)
#pragma unroll
      for (int j = 0; j < 4; ++j) {
        int d = n * 16 + lg * 4 + j;
        float yv = y[n][j] * inv;
        y[n][j] = yv;
        vv[n][j] = bf2f(vh[(size_t)d * TSEQ + q0 + l15]);
        dp += yv * vv[n][j];
      }
    dp += __shfl_xor(dp, 16);
    dp += __shfl_xor(dp, 32);
#pragma unroll
    for (int n = 0; n < 4; ++n)
#pragma unroll
      for (int j = 0; j < 4; ++j) {
        int d = n * 16 + lg * 4 + j;
        yw[l15 * 64 + (((d >> 3) ^ rx) << 3) + (d & 7)] = f2bf(y[n][j] - dp * vv[n][j]);
      }
    asm volatile("s_waitcnt lgkmcnt(0)" ::: "memory");
    int row = lane >> 2, quad = lane & 3;
    bf8v y0 = *(const bf8v*)(yw + row * 64 + ((quad ^ (row & 7)) << 3));
    bf8v y1 = *(const bf8v*)(yw + row * 64 + (((quad + 4) ^ (row & 7)) << 3));
    size_t gbase = ((size_t)(b * TSEQ + q0 + row)) * DIMC + h * HDIM + quad * 8;
    *(bf8v*)(ytil + gbase) = y0;
    *(bf8v*)(ytil + gbase + 32) = y1;
  }
}

extern "C" void kernel_launch(void* const* d_in, const int* in_sizes, int n_in,
                              void* d_out, int out_size, void* d_ws, size_t ws_size,
                              hipStream_t stream) {
  (void)in_sizes; (void)n_in; (void)out_size; (void)ws_size;
  const float* x  = (const float*)d_in[0];
  const float* Wq = (const float*)d_in[1];
  const float* Wk = (const float*)d_in[2];
  const float* Wv = (const float*)d_in[3];
  const float* Wp = (const float*)d_in[4];
  const float* qg = (const float*)d_in[5];
  float* out = (float*)d_out;
  char* ws = (char*)d_ws;
  const size_t KB = 1024, MB = 1ull << 20;

  ushort* xhi = (ushort*)(ws);                         // 8 MiB -> qhi
  ushort* xlo = (ushort*)(ws + 8 * MB);                // 8 MiB -> qlo
  ushort* xb  = (ushort*)(ws + 16 * MB);               // 8 MiB -> ytil
  ushort* wqkh = (ushort*)(ws + 24 * MB);              // 2.5 MiB (Wq|Wk hi)
  ushort* wqkl = (ushort*)(ws + 26 * MB + 512 * KB);   // 2.5 MiB (Wq|Wk lo)
  ushort* wvb = (ushort*)(ws + 29 * MB);               // 0.5 MiB
  ushort* wpb = (ushort*)(ws + 29 * MB + 512 * KB);    // 2 MiB
  float*  cosT = (float*)(ws + 31 * MB + 512 * KB);    // 0.25 MiB
  float*  sinT = (float*)(ws + 31 * MB + 768 * KB);    // 0.25 MiB
  float*  QKf  = (float*)(ws + 32 * MB);               // 20 MiB [4096][1280]
  ushort* kb16 = (ushort*)(ws + 52 * MB);              // 2 MiB
  ushort* vt2  = (ushort*)(ws + 54 * MB);              // 2 MiB
  ushort* vhat = (ushort*)(ws + 56 * MB);              // 2 MiB (total 58)

  float*  Vf   = out;                          // d_out scratch: 4 MiB (V f32)
  ushort* QKc  = (ushort*)((char*)out + 4 * MB); // d_out scratch: 10 MiB bf16
  ushort* qhb  = xhi;    // reuse after projections
  ushort* qlb  = xlo;
  ushort* ytil = xb;

  prep_all<<<6912, 256, 0, stream>>>(x, Wq, Wk, Wv, Wp, xhi, xlo, xb,
                                     wqkh, wqkl, wvb, wpb, cosT, sinT);

  gemm_qkv<<<704, 256, 0, stream>>>(xhi, xlo, wqkh, wqkl, QKf, QKc,
                                    xb, wvb, Vf);

  post_all<<<4352, 256, 0, stream>>>(QKf, QKc, cosT, sinT, qg, qhb, qlb, kb16,
                                     Vf, vt2, vhat);
  attn_kern<<<1024, 256, 0, stream>>>(qhb, qlb, kb16, vt2, vhat, ytil);
  gemm_bt<<<dim3(8, 32), 256, 0, stream>>>(ytil, wpb, out, 1024);
}